// Round 1
// baseline (643.586 us; speedup 1.0000x reference)
//
#include <hip/hip_runtime.h>
#include <hip/hip_bf16.h>

// Problem constants (match reference setup_inputs()).
#define U_DIM 128
#define NUM_OUT_SEG 16
#define C_DIM 300
#define S_DIM 32
#define NUM_X0 10
#define P1 32
#define P2 64
#define P3 96
#define P_TOT (P1 + P2 + P3)

// ---------------------------------------------------------------------------
// Prep kernel: sort the 192 paths by key = o*3 + (deg-1) into d_ws.
// ws layout:  soff[49] ints at offset 0  (boundaries of the 48 (o,deg) runs),
//             meta[192] int4 at offset 256: {w, idx0|idx1<<8|idx2<<16, c_bits, 0}
// Order within a run is irrelevant (summation commutes within tolerance).
// ---------------------------------------------------------------------------
__global__ void prep_kernel(const int* __restrict__ idx1, const int* __restrict__ w1,
                            const int* __restrict__ o1, const float* __restrict__ c1,
                            const int* __restrict__ idx2, const int* __restrict__ w2,
                            const int* __restrict__ o2, const float* __restrict__ c2,
                            const int* __restrict__ idx3, const int* __restrict__ w3,
                            const int* __restrict__ o3, const float* __restrict__ c3,
                            int* __restrict__ soff, int4* __restrict__ meta) {
    __shared__ int cnt[48];
    __shared__ int off[49];
    __shared__ int cur[48];
    int t = threadIdx.x;
    if (t < 48) cnt[t] = 0;
    __syncthreads();

    int key = -1, w = 0, packed = 0;
    float c = 0.f;
    if (t < P_TOT) {
        int deg, o, a0 = 0, a1 = 0, a2 = 0;
        if (t < P1) {
            int p = t;
            deg = 1; w = w1[p]; o = o1[p]; c = c1[p];
            a0 = idx1[p];
        } else if (t < P1 + P2) {
            int p = t - P1;
            deg = 2; w = w2[p]; o = o2[p]; c = c2[p];
            a0 = idx2[2 * p]; a1 = idx2[2 * p + 1];
        } else {
            int p = t - P1 - P2;
            deg = 3; w = w3[p]; o = o3[p]; c = c3[p];
            a0 = idx3[3 * p]; a1 = idx3[3 * p + 1]; a2 = idx3[3 * p + 2];
        }
        key = o * 3 + (deg - 1);
        packed = a0 | (a1 << 8) | (a2 << 16);
        atomicAdd(&cnt[key], 1);
    }
    __syncthreads();
    if (t == 0) {
        int a = 0;
        for (int k = 0; k < 48; ++k) { off[k] = a; a += cnt[k]; }
        off[48] = a;
    }
    __syncthreads();
    if (t < 49) soff[t] = off[t];
    if (t < 48) cur[t] = off[t];
    __syncthreads();
    if (t < P_TOT) {
        int r = atomicAdd(&cur[key], 1);
        meta[r] = make_int4(w, packed, __float_as_int(c), 0);
    }
}

// ---------------------------------------------------------------------------
// Main kernel: block = 128 threads = 4 batch rows x 32 float4-channel lanes.
// x1 rows staged in LDS (64 KB). Paths walked in (o, deg)-sorted order so the
// output-segment accumulator is one float4 register; stores are unconditional
// per (b, o) so the whole output is written every launch.
// ---------------------------------------------------------------------------
__global__ __launch_bounds__(128) void contract_kernel(
    const float* __restrict__ x0, const int* __restrict__ i0,
    const float* __restrict__ x1, const int* __restrict__ soff,
    const int4* __restrict__ meta, float* __restrict__ out) {
    // [s][bsub][u4] so each thread's dynamic-s reads hit its own slice.
    __shared__ float4 x1s[S_DIM][4][32];

    const int tid = threadIdx.x;
    const int bsub = tid >> 5;
    const int u4 = tid & 31;
    const long b = (long)blockIdx.x * 4 + bsub;

    // Stage this row of x1 into LDS as float4 (coalesced 16B/lane loads).
    const float4* x1p = (const float4*)(x1 + b * (S_DIM * U_DIM));
#pragma unroll
    for (int s = 0; s < S_DIM; ++s) {
        x1s[s][bsub][u4] = x1p[s * 32 + u4];
    }

    const float4* g0 = (const float4*)x0 + (long)i0[b] * (C_DIM * U_DIM / 4);
    float4* outb = (float4*)(out + b * (NUM_OUT_SEG * U_DIM));
    __syncthreads();

    int p = 0;
    for (int o = 0; o < NUM_OUT_SEG; ++o) {
        float4 acc = make_float4(0.f, 0.f, 0.f, 0.f);
        const int e1 = soff[o * 3 + 1];
        const int e2 = soff[o * 3 + 2];
        const int e3 = soff[o * 3 + 3];

        // degree-1 run
#pragma unroll 2
        for (; p < e1; ++p) {
            int4 m = meta[p];
            float cc = __int_as_float(m.z);
            float4 g = g0[(m.x << 5) + u4];
            float4 xa = x1s[m.y & 255][bsub][u4];
            acc.x = fmaf(cc * g.x, xa.x, acc.x);
            acc.y = fmaf(cc * g.y, xa.y, acc.y);
            acc.z = fmaf(cc * g.z, xa.z, acc.z);
            acc.w = fmaf(cc * g.w, xa.w, acc.w);
        }
        // degree-2 run
#pragma unroll 4
        for (; p < e2; ++p) {
            int4 m = meta[p];
            float cc = __int_as_float(m.z);
            float4 g = g0[(m.x << 5) + u4];
            float4 xa = x1s[m.y & 255][bsub][u4];
            float4 xb = x1s[(m.y >> 8) & 255][bsub][u4];
            float tx = xa.x * xb.x, ty = xa.y * xb.y, tz = xa.z * xb.z, tw = xa.w * xb.w;
            acc.x = fmaf(cc * g.x, tx, acc.x);
            acc.y = fmaf(cc * g.y, ty, acc.y);
            acc.z = fmaf(cc * g.z, tz, acc.z);
            acc.w = fmaf(cc * g.w, tw, acc.w);
        }
        // degree-3 run
#pragma unroll 4
        for (; p < e3; ++p) {
            int4 m = meta[p];
            float cc = __int_as_float(m.z);
            float4 g = g0[(m.x << 5) + u4];
            float4 xa = x1s[m.y & 255][bsub][u4];
            float4 xb = x1s[(m.y >> 8) & 255][bsub][u4];
            float4 xc = x1s[(m.y >> 16) & 255][bsub][u4];
            float tx = xa.x * xb.x * xc.x;
            float ty = xa.y * xb.y * xc.y;
            float tz = xa.z * xb.z * xc.z;
            float tw = xa.w * xb.w * xc.w;
            acc.x = fmaf(cc * g.x, tx, acc.x);
            acc.y = fmaf(cc * g.y, ty, acc.y);
            acc.z = fmaf(cc * g.z, tz, acc.z);
            acc.w = fmaf(cc * g.w, tw, acc.w);
        }
        outb[o * 32 + u4] = acc;
    }
}

extern "C" void kernel_launch(void* const* d_in, const int* in_sizes, int n_in,
                              void* d_out, int out_size, void* d_ws, size_t ws_size,
                              hipStream_t stream) {
    const float* x0 = (const float*)d_in[0];
    const int* i0 = (const int*)d_in[1];
    const float* x1 = (const float*)d_in[2];
    const int* idx1 = (const int*)d_in[3];
    const int* w1 = (const int*)d_in[4];
    const int* o1 = (const int*)d_in[5];
    const float* c1 = (const float*)d_in[6];
    const int* idx2 = (const int*)d_in[7];
    const int* w2 = (const int*)d_in[8];
    const int* o2 = (const int*)d_in[9];
    const float* c2 = (const float*)d_in[10];
    const int* idx3 = (const int*)d_in[11];
    const int* w3 = (const int*)d_in[12];
    const int* o3 = (const int*)d_in[13];
    const float* c3 = (const float*)d_in[14];

    int* soff = (int*)d_ws;
    int4* meta = (int4*)((char*)d_ws + 256);

    const int B = in_sizes[1];  // 16384

    prep_kernel<<<1, 256, 0, stream>>>(idx1, w1, o1, c1, idx2, w2, o2, c2,
                                       idx3, w3, o3, c3, soff, meta);
    contract_kernel<<<B / 4, 128, 0, stream>>>(x0, i0, x1, soff, meta, (float*)d_out);
}

// Round 3
// 504.983 us; speedup vs baseline: 1.2745x; 1.2745x over previous
//
#include <hip/hip_runtime.h>
#include <hip/hip_bf16.h>

// Problem constants (match reference setup_inputs()).
#define U_DIM 128
#define NUM_OUT_SEG 16
#define C_DIM 300
#define S_DIM 32
#define NUM_X0 10
#define P1 32
#define P2 64
#define P3 96
#define P_TOT (P1 + P2 + P3)

typedef float vfloat4 __attribute__((ext_vector_type(4)));  // clang-native, OK for nontemporal builtins

// ---------------------------------------------------------------------------
// Prep kernel: sort the 192 paths by key = o*3 + (deg-1) into d_ws.
// ws layout:  soff[49] ints at offset 0  (boundaries of the 48 (o,deg) runs),
//             meta[192] int4 at offset 256: {w, idx0|idx1<<8|idx2<<16, c_bits, 0}
// Order within a run is irrelevant (summation commutes within tolerance).
// ---------------------------------------------------------------------------
__global__ void prep_kernel(const int* __restrict__ idx1, const int* __restrict__ w1,
                            const int* __restrict__ o1, const float* __restrict__ c1,
                            const int* __restrict__ idx2, const int* __restrict__ w2,
                            const int* __restrict__ o2, const float* __restrict__ c2,
                            const int* __restrict__ idx3, const int* __restrict__ w3,
                            const int* __restrict__ o3, const float* __restrict__ c3,
                            int* __restrict__ soff, int4* __restrict__ meta) {
    __shared__ int cnt[48];
    __shared__ int off[49];
    __shared__ int cur[48];
    int t = threadIdx.x;
    if (t < 48) cnt[t] = 0;
    __syncthreads();

    int key = -1, w = 0, packed = 0;
    float c = 0.f;
    if (t < P_TOT) {
        int deg, o, a0 = 0, a1 = 0, a2 = 0;
        if (t < P1) {
            int p = t;
            deg = 1; w = w1[p]; o = o1[p]; c = c1[p];
            a0 = idx1[p];
        } else if (t < P1 + P2) {
            int p = t - P1;
            deg = 2; w = w2[p]; o = o2[p]; c = c2[p];
            a0 = idx2[2 * p]; a1 = idx2[2 * p + 1];
        } else {
            int p = t - P1 - P2;
            deg = 3; w = w3[p]; o = o3[p]; c = c3[p];
            a0 = idx3[3 * p]; a1 = idx3[3 * p + 1]; a2 = idx3[3 * p + 2];
        }
        key = o * 3 + (deg - 1);
        packed = a0 | (a1 << 8) | (a2 << 16);
        atomicAdd(&cnt[key], 1);
    }
    __syncthreads();
    if (t == 0) {
        int a = 0;
        for (int k = 0; k < 48; ++k) { off[k] = a; a += cnt[k]; }
        off[48] = a;
    }
    __syncthreads();
    if (t < 49) soff[t] = off[t];
    if (t < 48) cur[t] = off[t];
    __syncthreads();
    if (t < P_TOT) {
        int r = atomicAdd(&cur[key], 1);
        meta[r] = make_int4(w, packed, __float_as_int(c), 0);
    }
}

// ---------------------------------------------------------------------------
// Main kernel: block = 256 threads = 1 batch row; 8 groups of 32 float4-lanes,
// group g handles output segments {2g, 2g+1}. LDS = one 16 KB x1 row →
// 4 blocks/CU (launch_bounds caps VGPR<=128) = 16 waves/CU = 50% occupancy,
// vs 11.7% in round 1 (the latency-bound culprit).
// ---------------------------------------------------------------------------
__global__ __launch_bounds__(256, 4) void contract_kernel(
    const float* __restrict__ x0, const int* __restrict__ i0,
    const float* __restrict__ x1, const int* __restrict__ soff,
    const int4* __restrict__ meta, float* __restrict__ out) {
    __shared__ vfloat4 x1s[S_DIM * 32];  // one full x1 row: [s][u4], 16 KB

    const int tid = threadIdx.x;
    const int g = tid >> 5;   // output-segment group 0..7
    const int u4 = tid & 31;  // float4 channel lane
    const long b = blockIdx.x;

    // Stage this row of x1 into LDS (coalesced 16B/lane, 4 float4 per thread).
    const vfloat4* x1p = (const vfloat4*)(x1 + b * (S_DIM * U_DIM));
#pragma unroll
    for (int k = 0; k < 4; ++k) {
        x1s[k * 256 + tid] = x1p[k * 256 + tid];
    }

    const vfloat4* g0 = (const vfloat4*)x0 + (long)i0[b] * (C_DIM * 32);
    vfloat4* outb = (vfloat4*)(out + b * (NUM_OUT_SEG * U_DIM));
    __syncthreads();

#pragma unroll
    for (int oo = 0; oo < 2; ++oo) {
        const int o = g * 2 + oo;
        vfloat4 acc = (vfloat4)(0.f);
        int p = soff[o * 3];
        const int e1 = soff[o * 3 + 1];
        const int e2 = soff[o * 3 + 2];
        const int e3 = soff[o * 3 + 3];

        // degree-1 run
        for (; p < e1; ++p) {
            int4 m = meta[p];
            float cc = __int_as_float(m.z);
            vfloat4 gg = g0[(m.x << 5) + u4];
            vfloat4 xa = x1s[((m.y & 255) << 5) + u4];
            acc += (cc * gg) * xa;
        }
        // degree-2 run
#pragma unroll 2
        for (; p < e2; ++p) {
            int4 m = meta[p];
            float cc = __int_as_float(m.z);
            vfloat4 gg = g0[(m.x << 5) + u4];
            vfloat4 xa = x1s[((m.y & 255) << 5) + u4];
            vfloat4 xb = x1s[(((m.y >> 8) & 255) << 5) + u4];
            acc += (cc * gg) * (xa * xb);
        }
        // degree-3 run
#pragma unroll 2
        for (; p < e3; ++p) {
            int4 m = meta[p];
            float cc = __int_as_float(m.z);
            vfloat4 gg = g0[(m.x << 5) + u4];
            vfloat4 xa = x1s[((m.y & 255) << 5) + u4];
            vfloat4 xb = x1s[(((m.y >> 8) & 255) << 5) + u4];
            vfloat4 xc = x1s[(((m.y >> 16) & 255) << 5) + u4];
            acc += (cc * gg) * (xa * xb * xc);
        }
        // Streamed output, no reuse: keep it out of L2/L3.
        __builtin_nontemporal_store(acc, &outb[o * 32 + u4]);
    }
}

extern "C" void kernel_launch(void* const* d_in, const int* in_sizes, int n_in,
                              void* d_out, int out_size, void* d_ws, size_t ws_size,
                              hipStream_t stream) {
    const float* x0 = (const float*)d_in[0];
    const int* i0 = (const int*)d_in[1];
    const float* x1 = (const float*)d_in[2];
    const int* idx1 = (const int*)d_in[3];
    const int* w1 = (const int*)d_in[4];
    const int* o1 = (const int*)d_in[5];
    const float* c1 = (const float*)d_in[6];
    const int* idx2 = (const int*)d_in[7];
    const int* w2 = (const int*)d_in[8];
    const int* o2 = (const int*)d_in[9];
    const float* c2 = (const float*)d_in[10];
    const int* idx3 = (const int*)d_in[11];
    const int* w3 = (const int*)d_in[12];
    const int* o3 = (const int*)d_in[13];
    const float* c3 = (const float*)d_in[14];

    int* soff = (int*)d_ws;
    int4* meta = (int4*)((char*)d_ws + 256);

    const int B = in_sizes[1];  // 16384

    prep_kernel<<<1, 256, 0, stream>>>(idx1, w1, o1, c1, idx2, w2, o2, c2,
                                       idx3, w3, o3, c3, soff, meta);
    contract_kernel<<<B, 256, 0, stream>>>(x0, i0, x1, soff, meta, (float*)d_out);
}